// Round 1
// baseline (210.338 us; speedup 1.0000x reference)
//
#include <hip/hip_runtime.h>

#define EPS 1e-5f
#define PROJ_EPS 1e-5f
#define MAX_TANH_ARG 15.0f

typedef __bf16 bf16x8 __attribute__((ext_vector_type(8)));
typedef float f32x4 __attribute__((ext_vector_type(4)));

__device__ __forceinline__ unsigned short f2bf(float f) {
  unsigned u = __builtin_bit_cast(unsigned, f);
  u += 0x7fffu + ((u >> 16) & 1u);   // round-to-nearest-even
  return (unsigned short)(u >> 16);
}
__device__ __forceinline__ float bf2f(unsigned short h) {
  return __builtin_bit_cast(float, ((unsigned)h) << 16);
}

union BF8 {
  unsigned short u[8];
  bf16x8 v;
  uint4 q;
};

// ---------------------------------------------------------------------------
// Pack W[layer][k][n] (fp32) into bf16 B-fragment order for 16x16x32 MFMA:
// wpack[((layer*32 + t*4 + s)*64 + lane)*8 + j] = bf16(W[layer][s*32+quad*8+j][t*16+(lane&15)])
// ---------------------------------------------------------------------------
__global__ void pack_w_kernel(const float* __restrict__ W,
                              unsigned short* __restrict__ wpack) {
  int tid = blockIdx.x * blockDim.x + threadIdx.x;  // 0..4095
  if (tid >= 2 * 8 * 4 * 64) return;
  int lane = tid & 63;
  int s = (tid >> 6) & 3;
  int t = (tid >> 8) & 7;
  int layer = tid >> 11;
  int quad = lane >> 4;
  int n = t * 16 + (lane & 15);
  unsigned short* dst = wpack + ((size_t)((layer * 32 + t * 4 + s) * 64 + lane)) * 8;
  const float* src = W + (size_t)layer * 16384;
#pragma unroll
  for (int j = 0; j < 8; ++j) {
    int k = s * 32 + quad * 8 + j;
    dst[j] = f2bf(src[(size_t)k * 128 + n]);
  }
}

// ---------------------------------------------------------------------------
// msg[row,:] = (scale[row] * x[row,:]) @ W  using mfma_f32_16x16x32_bf16.
// MODE 0: x = fp32 node_repr, scale = mask.  MODE 1: x = bf16 x1, scale = ls.
// Block = 256 thr = 4 waves; wave handles 16 rows x 128 cols; block = 64 rows.
// ---------------------------------------------------------------------------
template <int MODE>
__global__ __launch_bounds__(256) void gemm_kernel(
    const float* __restrict__ xf, const unsigned short* __restrict__ xb,
    const float* __restrict__ scale_in, const unsigned short* __restrict__ wpack,
    unsigned short* __restrict__ msg, int N) {
  const int lane = threadIdx.x & 63;
  const int wv = threadIdx.x >> 6;
  const int m = lane & 15;
  const int quad = lane >> 4;
  const int base = blockIdx.x * 64 + wv * 16;
  const int row = base + m;
  const int rowc = row < N ? row : N - 1;
  const float scale = (row < N) ? scale_in[rowc] : 0.0f;

  f32x4 acc[8];
#pragma unroll
  for (int t = 0; t < 8; ++t) acc[t] = (f32x4){0.f, 0.f, 0.f, 0.f};

#pragma unroll
  for (int sk = 0; sk < 4; ++sk) {
    const int k0 = sk * 32 + quad * 8;
    BF8 a;
    if (MODE == 0) {
      const float4* xp = (const float4*)(xf + (size_t)rowc * 128 + k0);
      float4 p0 = xp[0], p1 = xp[1];
      a.u[0] = f2bf(p0.x * scale); a.u[1] = f2bf(p0.y * scale);
      a.u[2] = f2bf(p0.z * scale); a.u[3] = f2bf(p0.w * scale);
      a.u[4] = f2bf(p1.x * scale); a.u[5] = f2bf(p1.y * scale);
      a.u[6] = f2bf(p1.z * scale); a.u[7] = f2bf(p1.w * scale);
    } else {
      BF8 r;
      r.q = *(const uint4*)(xb + (size_t)rowc * 128 + k0);
#pragma unroll
      for (int j = 0; j < 8; ++j) a.u[j] = f2bf(bf2f(r.u[j]) * scale);
    }
#pragma unroll
    for (int t = 0; t < 8; ++t) {
      BF8 b;
      b.q = *(const uint4*)(wpack + (size_t)((t * 4 + sk) * 64 + lane) * 8);
      acc[t] = __builtin_amdgcn_mfma_f32_16x16x32_bf16(a.v, b.v, acc[t], 0, 0, 0);
    }
  }

  // C/D layout: col = t*16 + (lane&15), row = base + quad*4 + reg
#pragma unroll
  for (int t = 0; t < 8; ++t) {
    const int c = t * 16 + m;
#pragma unroll
    for (int r = 0; r < 4; ++r) {
      const int rr = base + quad * 4 + r;
      if (rr < N) msg[(size_t)rr * 128 + c] = f2bf(acc[t][r]);
    }
  }
}

// ---------------------------------------------------------------------------
// Per node n: acc = sum_k w[n,k] * msg[adj[n,k],:]; x = relu(expmap0(acc)).
// MODE 0: store bf16 x1 + log-map scale ls[n].  MODE 1: store fp32 out.
// One wave per node; lane owns cols (2*lane, 2*lane+1).
// ---------------------------------------------------------------------------
template <int MODE>
__global__ __launch_bounds__(256) void gather_kernel(
    const unsigned short* __restrict__ msg, const int* __restrict__ adj,
    const float* __restrict__ wgt, unsigned short* __restrict__ x1out,
    float* __restrict__ lsout, float* __restrict__ out, int N) {
  const int lane = threadIdx.x & 63;
  const int gw = (int)((blockIdx.x * blockDim.x + threadIdx.x) >> 6);
  const int nw = (int)((gridDim.x * blockDim.x) >> 6);
  for (int n = gw; n < N; n += nw) {
    int idxv = 0;
    float wv = 0.f;
    if (lane < 32) {
      idxv = adj[(size_t)n * 32 + lane];
      wv = wgt[(size_t)n * 32 + lane];
    }
    float a0 = 0.f, a1 = 0.f;
#pragma unroll
    for (int k = 0; k < 32; ++k) {
      const int id = __shfl(idxv, k);
      const float wk = __shfl(wv, k);
      const unsigned pr = *(const unsigned*)(msg + (size_t)id * 128 + 2 * lane);
      a0 = fmaf(wk, bf2f((unsigned short)(pr & 0xffffu)), a0);
      a1 = fmaf(wk, bf2f((unsigned short)(pr >> 16)), a1);
    }
    // exp_map_zero + relu
    float s2 = a0 * a0 + a1 * a1;
#pragma unroll
    for (int o = 32; o > 0; o >>= 1) s2 += __shfl_xor(s2, o);
    const float nrm = sqrtf(s2);
    const float ncl = fminf(fmaxf(nrm, EPS), MAX_TANH_ARG);
    const float esc = tanhf(ncl) / fmaxf(nrm, EPS);
    const float v0 = fmaxf(esc * a0, 0.f);
    const float v1 = fmaxf(esc * a1, 0.f);
    if (MODE == 0) {
      const unsigned pk = (unsigned)f2bf(v0) | ((unsigned)f2bf(v1) << 16);
      *(unsigned*)(x1out + (size_t)n * 128 + 2 * lane) = pk;
      // log-map scale for the next layer: arctanh(clip(|x|)) / max(|x|, eps)
      float r2 = v0 * v0 + v1 * v1;
#pragma unroll
      for (int o = 32; o > 0; o >>= 1) r2 += __shfl_xor(r2, o);
      const float nr = sqrtf(r2);
      const float nc2 = fminf(fmaxf(nr, EPS), 1.0f - PROJ_EPS);
      const float ls = 0.5f * logf((1.0f + nc2) / (1.0f - nc2)) / fmaxf(nr, EPS);
      if (lane == 0) lsout[n] = ls;
    } else {
      *(float2*)(out + (size_t)n * 128 + 2 * lane) = make_float2(v0, v1);
    }
  }
}

extern "C" void kernel_launch(void* const* d_in, const int* in_sizes, int n_in,
                              void* d_out, int out_size, void* d_ws, size_t ws_size,
                              hipStream_t stream) {
  const float* node = (const float*)d_in[0];        // [N,128] fp32
  const int* adj = (const int*)d_in[1];             // [N,32] int32
  const float* wgt = (const float*)d_in[2];         // [N,32] fp32
  const float* mask = (const float*)d_in[3];        // [N,1] fp32
  const float* mw = (const float*)d_in[4];          // [2,128,128] fp32
  float* out = (float*)d_out;
  const int N = in_sizes[0] / 128;

  // workspace layout: wpack (64 KiB) | ls (N fp32, 256B-aligned) | msg (N*128 bf16)
  char* ws = (char*)d_ws;
  unsigned short* wpack = (unsigned short*)ws;
  float* ls = (float*)(ws + 65536);
  size_t ls_bytes = ((size_t)N * 4 + 255) & ~(size_t)255;
  unsigned short* msg = (unsigned short*)(ws + 65536 + ls_bytes);
  // x1 (bf16, N*128 = half of d_out) lives in d_out; dead before final write
  unsigned short* x1 = (unsigned short*)d_out;

  hipLaunchKernelGGL(pack_w_kernel, dim3(16), dim3(256), 0, stream, mw, wpack);
  const int gb = (N + 63) / 64;
  hipLaunchKernelGGL((gemm_kernel<0>), dim3(gb), dim3(256), 0, stream,
                     node, (const unsigned short*)nullptr, mask, wpack, msg, N);
  hipLaunchKernelGGL((gather_kernel<0>), dim3(1024), dim3(256), 0, stream,
                     msg, adj, wgt, x1, ls, (float*)nullptr, N);
  hipLaunchKernelGGL((gemm_kernel<1>), dim3(gb), dim3(256), 0, stream,
                     (const float*)nullptr, x1, ls, wpack + 16384, msg, N);
  hipLaunchKernelGGL((gather_kernel<1>), dim3(1024), dim3(256), 0, stream,
                     msg, adj, wgt, (unsigned short*)nullptr, (float*)nullptr, out, N);
}